// Round 1
// baseline (750.930 us; speedup 1.0000x reference)
//
#include <hip/hip_runtime.h>

// p,q [64,64,25000] fp32. loss = sum_{rows} mask(row) * sum_v q*(log q - log p) / 4096
// mask(row) = 0 iff argmax_v p[row] == 0  <=>  p[row][0] >= max_v p[row] (first-occurrence rule).
//
// Memory-bound: 819.2 MB read once -> ~130 us floor at 6.3 TB/s.
// This version vs previous (717 us):
//  - removed __builtin_nontemporal_load (nt has no upside for a once-streamed
//    input and is the prime suspect for the 5.5x gap to the BW roofline)
//  - __log2f + single final x ln2 (v_log_f32 without the per-element ln2 mul)
//  - batch-of-4 chunk loads (8 loads issued back-to-back per iter, 4 indep accumulators)

#define VOCAB   25000
#define VOCAB4  6250          // 25000 / 4, exact; rows are 16B-aligned (100000 % 16 == 0)
#define BLOCK   256
#define BATCH   4
#define FULL_ITERS 6          // 6 * BATCH * BLOCK = 6144 chunks; remainder = 106
#define LN2 0.69314718055994530942f

typedef float f4 __attribute__((ext_vector_type(4)));

__global__ __launch_bounds__(BLOCK) void kl_row_kernel(
    const float* __restrict__ p, const float* __restrict__ q,
    float* __restrict__ partial)
{
    const int row = blockIdx.x;
    const size_t base = (size_t)row * VOCAB;
    const f4* __restrict__ p4 = reinterpret_cast<const f4*>(p + base);
    const f4* __restrict__ q4 = reinterpret_cast<const f4*>(q + base);
    const int tid = threadIdx.x;

    // p[row][0], needed for the mask (only lane 0's value is used)
    float p0 = (tid == 0) ? p[base] : 0.0f;

    float s[BATCH]  = {0.f, 0.f, 0.f, 0.f};
    float mx[BATCH] = {-1.f, -1.f, -1.f, -1.f};   // probabilities are positive

    int v = tid;
    for (int i = 0; i < FULL_ITERS; ++i, v += BATCH * BLOCK) {
        f4 P[BATCH], Q[BATCH];
        // issue all 8 independent loads before any compute
        #pragma unroll
        for (int b = 0; b < BATCH; ++b) P[b] = p4[v + b * BLOCK];
        #pragma unroll
        for (int b = 0; b < BATCH; ++b) Q[b] = q4[v + b * BLOCK];

        #pragma unroll
        for (int b = 0; b < BATCH; ++b) {
            #pragma unroll
            for (int k = 0; k < 4; ++k)
                s[b] = fmaf(Q[b][k], __log2f(Q[b][k]) - __log2f(P[b][k]), s[b]);
            mx[b] = fmaxf(mx[b],
                     fmaxf(fmaxf(P[b][0], P[b][1]), fmaxf(P[b][2], P[b][3])));
        }
    }

    // remainder: chunks 6144..6249 (106 chunks)
    if (tid < (VOCAB4 - FULL_ITERS * BATCH * BLOCK)) {
        const int vr = FULL_ITERS * BATCH * BLOCK + tid;
        f4 P = p4[vr];
        f4 Q = q4[vr];
        #pragma unroll
        for (int k = 0; k < 4; ++k)
            s[0] = fmaf(Q[k], __log2f(Q[k]) - __log2f(P[k]), s[0]);
        mx[0] = fmaxf(mx[0], fmaxf(fmaxf(P[0], P[1]), fmaxf(P[2], P[3])));
    }

    float sum  = (s[0] + s[1]) + (s[2] + s[3]);
    float pmax = fmaxf(fmaxf(mx[0], mx[1]), fmaxf(mx[2], mx[3]));

    // wave(64) shuffle reduction
    #pragma unroll
    for (int off = 32; off > 0; off >>= 1) {
        sum  += __shfl_down(sum, off, 64);
        pmax  = fmaxf(pmax, __shfl_down(pmax, off, 64));
    }

    __shared__ float ssum[BLOCK / 64];
    __shared__ float smax[BLOCK / 64];
    const int wave = tid >> 6;
    const int lane = tid & 63;
    if (lane == 0) { ssum[wave] = sum; smax[wave] = pmax; }
    __syncthreads();

    if (tid == 0) {
        float stot = (ssum[0] + ssum[1]) + (ssum[2] + ssum[3]);
        float m = fmaxf(fmaxf(smax[0], smax[1]), fmaxf(smax[2], smax[3]));
        // mask = (argmax != 0); argmax==0 iff p0 == rowmax (first-occurrence rule)
        partial[row] = (p0 < m) ? stot * LN2 : 0.0f;
    }
}

__global__ __launch_bounds__(BLOCK) void kl_final_reduce(
    const float* __restrict__ partial, int rows, float* __restrict__ out)
{
    const int tid = threadIdx.x;
    float sum = 0.0f;
    for (int i = tid; i < rows; i += BLOCK) sum += partial[i];

    #pragma unroll
    for (int off = 32; off > 0; off >>= 1)
        sum += __shfl_down(sum, off, 64);

    __shared__ float ssum[BLOCK / 64];
    const int wave = tid >> 6;
    const int lane = tid & 63;
    if (lane == 0) ssum[wave] = sum;
    __syncthreads();

    if (tid == 0) {
        float s = (ssum[0] + ssum[1]) + (ssum[2] + ssum[3]);
        out[0] = s / (float)rows;
    }
}

extern "C" void kernel_launch(void* const* d_in, const int* in_sizes, int n_in,
                              void* d_out, int out_size, void* d_ws, size_t ws_size,
                              hipStream_t stream)
{
    const float* p = (const float*)d_in[0];
    const float* q = (const float*)d_in[1];
    float* out = (float*)d_out;
    float* partial = (float*)d_ws;          // rows * 4 B = 16 KB

    const int rows = in_sizes[0] / VOCAB;   // 64*64 = 4096

    kl_row_kernel<<<rows, BLOCK, 0, stream>>>(p, q, partial);
    kl_final_reduce<<<1, BLOCK, 0, stream>>>(partial, rows, out);
}

// Round 2
// 710.638 us; speedup vs baseline: 1.0567x; 1.0567x over previous
//
#include <hip/hip_runtime.h>

// p,q [64,64,25000] fp32. loss = sum_{rows} mask(row) * sum_v q*(log q - log p) / 4096
// mask(row) = 0 iff argmax_v p[row] == 0  <=>  p[row][0] >= max_v p[row] (first-occurrence rule).
//
// Memory-bound: 819.2 MB read once -> ~126-130 us floor at 6.3-6.5 TB/s
// (harness fill kernels prove 6.5 TB/s is sustainable on this footprint).
// Bench total includes ~500 us of harness re-poison fills we cannot remove.
//
// R1 lesson: removing nontemporal loads regressed ~30 us (717 -> 751 cross-session).
// This version: nt restored + BATCH=8 (16 independent 16B loads in flight before
// the log dependency chain) + __log2f with a single final x ln2.

#define VOCAB   25000
#define VOCAB4  6250          // 25000 / 4 exact; rows are 16B-aligned (100000 % 16 == 0)
#define BLOCK   256
#define BATCH   8
#define FULL_ITERS 3          // 3 * BATCH * BLOCK = 6144 chunks; remainder = 106
#define LN2 0.69314718055994530942f

typedef float f4 __attribute__((ext_vector_type(4)));

__global__ __launch_bounds__(BLOCK) void kl_row_kernel(
    const float* __restrict__ p, const float* __restrict__ q,
    float* __restrict__ partial)
{
    const int row = blockIdx.x;
    const size_t base = (size_t)row * VOCAB;
    const f4* __restrict__ p4 = reinterpret_cast<const f4*>(p + base);
    const f4* __restrict__ q4 = reinterpret_cast<const f4*>(q + base);
    const int tid = threadIdx.x;

    // p[row][0], needed for the mask (only lane 0's value is used)
    float p0 = (tid == 0) ? p[base] : 0.0f;

    float s[BATCH]  = {0.f, 0.f, 0.f, 0.f, 0.f, 0.f, 0.f, 0.f};
    float mx[BATCH] = {-1.f, -1.f, -1.f, -1.f, -1.f, -1.f, -1.f, -1.f};

    int v = tid;
    for (int i = 0; i < FULL_ITERS; ++i, v += BATCH * BLOCK) {
        f4 P[BATCH], Q[BATCH];
        // issue all 16 independent loads before any compute
        #pragma unroll
        for (int b = 0; b < BATCH; ++b)
            P[b] = __builtin_nontemporal_load(&p4[v + b * BLOCK]);
        #pragma unroll
        for (int b = 0; b < BATCH; ++b)
            Q[b] = __builtin_nontemporal_load(&q4[v + b * BLOCK]);

        #pragma unroll
        for (int b = 0; b < BATCH; ++b) {
            #pragma unroll
            for (int k = 0; k < 4; ++k)
                s[b] = fmaf(Q[b][k], __log2f(Q[b][k]) - __log2f(P[b][k]), s[b]);
            mx[b] = fmaxf(mx[b],
                     fmaxf(fmaxf(P[b][0], P[b][1]), fmaxf(P[b][2], P[b][3])));
        }
    }

    // remainder: chunks 6144..6249 (106 chunks)
    if (tid < (VOCAB4 - FULL_ITERS * BATCH * BLOCK)) {
        const int vr = FULL_ITERS * BATCH * BLOCK + tid;
        f4 P = __builtin_nontemporal_load(&p4[vr]);
        f4 Q = __builtin_nontemporal_load(&q4[vr]);
        #pragma unroll
        for (int k = 0; k < 4; ++k)
            s[0] = fmaf(Q[k], __log2f(Q[k]) - __log2f(P[k]), s[0]);
        mx[0] = fmaxf(mx[0], fmaxf(fmaxf(P[0], P[1]), fmaxf(P[2], P[3])));
    }

    float sum = 0.f, pmax = -1.f;
    #pragma unroll
    for (int b = 0; b < BATCH; ++b) { sum += s[b]; pmax = fmaxf(pmax, mx[b]); }

    // wave(64) shuffle reduction
    #pragma unroll
    for (int off = 32; off > 0; off >>= 1) {
        sum  += __shfl_down(sum, off, 64);
        pmax  = fmaxf(pmax, __shfl_down(pmax, off, 64));
    }

    __shared__ float ssum[BLOCK / 64];
    __shared__ float smax[BLOCK / 64];
    const int wave = tid >> 6;
    const int lane = tid & 63;
    if (lane == 0) { ssum[wave] = sum; smax[wave] = pmax; }
    __syncthreads();

    if (tid == 0) {
        float stot = (ssum[0] + ssum[1]) + (ssum[2] + ssum[3]);
        float m = fmaxf(fmaxf(smax[0], smax[1]), fmaxf(smax[2], smax[3]));
        // mask = (argmax != 0); argmax==0 iff p0 == rowmax (first-occurrence rule)
        partial[row] = (p0 < m) ? stot * LN2 : 0.0f;
    }
}

__global__ __launch_bounds__(BLOCK) void kl_final_reduce(
    const float* __restrict__ partial, int rows, float* __restrict__ out)
{
    const int tid = threadIdx.x;
    float sum = 0.0f;
    for (int i = tid; i < rows; i += BLOCK) sum += partial[i];

    #pragma unroll
    for (int off = 32; off > 0; off >>= 1)
        sum += __shfl_down(sum, off, 64);

    __shared__ float ssum[BLOCK / 64];
    const int wave = tid >> 6;
    const int lane = tid & 63;
    if (lane == 0) ssum[wave] = sum;
    __syncthreads();

    if (tid == 0) {
        float s = (ssum[0] + ssum[1]) + (ssum[2] + ssum[3]);
        out[0] = s / (float)rows;
    }
}

extern "C" void kernel_launch(void* const* d_in, const int* in_sizes, int n_in,
                              void* d_out, int out_size, void* d_ws, size_t ws_size,
                              hipStream_t stream)
{
    const float* p = (const float*)d_in[0];
    const float* q = (const float*)d_in[1];
    float* out = (float*)d_out;
    float* partial = (float*)d_ws;          // rows * 4 B = 16 KB

    const int rows = in_sizes[0] / VOCAB;   // 64*64 = 4096

    kl_row_kernel<<<rows, BLOCK, 0, stream>>>(p, q, partial);
    kl_final_reduce<<<1, BLOCK, 0, stream>>>(partial, rows, out);
}